// Round 7
// baseline (1790.785 us; speedup 1.0000x reference)
//
#include <hip/hip_runtime.h>
#include <math.h>

#define BQ 8
#define PP 196
#define DD 2048
#define AA 700
#define HH 700
#define EE 700
#define VV 30000
#define NSTEP 30
#define G4 2800
#define NA 2748    // A cols: att2(700) + gLin(2048)
#define KD 3448    // D1 virtual K: emb(700) + awe(2048) + h(700)

#define KSA 8
#define KRA 88
#define NCBA 11

#define KSD 48
#define KRD 72
#define NCBD 11

#define KSE 6
#define KRE 117
#define NCBE 118
#define NB2 235    // E2 blocks
#define NBB 392    // B blocks

__device__ __forceinline__ float sigm(float x) { return 1.f / (1.f + expf(-x)); }

// -------- prologue: mean over pixels; also zero g_arg --------
__global__ __launch_bounds__(256) void k_mean(const float* __restrict__ enc,
                                              float* __restrict__ mean,
                                              unsigned long long* __restrict__ g_arg) {
    if (blockIdx.x == 0 && threadIdx.x < NSTEP * 8) g_arg[threadIdx.x] = 0ULL;
    int b = blockIdx.x >> 3;
    int d = ((blockIdx.x & 7) << 8) + threadIdx.x;
    const float* p = enc + (size_t)b * PP * DD + d;
    float s = 0.f;
    for (int i = 0; i < PP; i++) s += p[(size_t)i * DD];
    mean[b * DD + d] = s * (1.0f / PP);
}

// -------- prologue: h0 / c0 --------
__global__ __launch_bounds__(256) void k_init_hc(const float* __restrict__ mean,
    const float* __restrict__ Wh, const float* __restrict__ bh,
    const float* __restrict__ Wc, const float* __restrict__ bc,
    float* __restrict__ h, float* __restrict__ c) {
    __shared__ float X[BQ][DD];
    __shared__ float red[4][64][BQ];
    int tid = threadIdx.x;
    for (int i = tid; i < BQ * DD; i += 256) X[i / DD][i % DD] = mean[i];
    __syncthreads();
    int j = blockIdx.x * 64 + (tid & 63);
    int kq = tid >> 6;
    float acc[BQ];
    #pragma unroll
    for (int b = 0; b < BQ; b++) acc[b] = 0.f;
    if (j < 2 * HH) {
        bool isH = j < HH;
        int col = isH ? j : j - HH;
        const float* wp = (isH ? Wh : Wc) + (size_t)(kq * 512) * HH + col;
        for (int k = kq * 512; k < kq * 512 + 512; k++) {
            float wv = *wp; wp += HH;
            #pragma unroll
            for (int b = 0; b < BQ; b++) acc[b] += X[b][k] * wv;
        }
    }
    #pragma unroll
    for (int b = 0; b < BQ; b++) red[kq][tid & 63][b] = acc[b];
    __syncthreads();
    for (int idx = tid; idx < 512; idx += 256) {
        int jj = idx >> 3, b = idx & 7;
        int jg = blockIdx.x * 64 + jj;
        if (jg >= 2 * HH) continue;
        float s = red[0][jj][b] + red[1][jj][b] + red[2][jj][b] + red[3][jj][b];
        bool isH = jg < HH;
        int col = isH ? jg : jg - HH;
        s += isH ? bh[col] : bc[col];
        (isH ? h : c)[b * HH + col] = s;
    }
}

// -------- prologue: att1 partials, 32x64 tile, k split 2 --------
__global__ __launch_bounds__(256) void k_att1(const float* __restrict__ Aenc,
    const float* __restrict__ W, float* __restrict__ out0,
    float* __restrict__ out1) {
    const int M = BQ * PP; // 1568
    __shared__ float As[16][36];
    __shared__ float Bs[16][68];
    int bm = blockIdx.x, bn = blockIdx.y, bz = blockIdx.z;
    int tid = threadIdx.x;
    int tx = tid & 15, ty = tid >> 4;   // ty in 0..15
    float acc[2][4] = {};
    int kbeg = bz * 1024, kend = kbeg + 1024;
    for (int kt = kbeg; kt < kend; kt += 16) {
        if (tid < 128) {
            int row = tid >> 2, k4 = (tid & 3) * 4;
            int grow = bm * 32 + row;
            float4 v = make_float4(0.f, 0.f, 0.f, 0.f);
            if (grow < M) v = *(const float4*)&Aenc[(size_t)grow * DD + kt + k4];
            As[k4 + 0][row] = v.x; As[k4 + 1][row] = v.y;
            As[k4 + 2][row] = v.z; As[k4 + 3][row] = v.w;
        }
        {
            int rk = tid >> 4, n4 = (tid & 15) * 4;
            int col = bn * 64 + n4;
            float4 wv = make_float4(0.f, 0.f, 0.f, 0.f);
            if (col < AA) wv = *(const float4*)&W[(size_t)(kt + rk) * AA + col];
            *(float4*)&Bs[rk][n4] = wv;
        }
        __syncthreads();
        #pragma unroll
        for (int k = 0; k < 16; k++) {
            float a0 = As[k][ty * 2];
            float a1 = As[k][ty * 2 + 1];
            float4 bv = *(const float4*)&Bs[k][tx * 4];
            acc[0][0] += a0 * bv.x; acc[0][1] += a0 * bv.y;
            acc[0][2] += a0 * bv.z; acc[0][3] += a0 * bv.w;
            acc[1][0] += a1 * bv.x; acc[1][1] += a1 * bv.y;
            acc[1][2] += a1 * bv.z; acc[1][3] += a1 * bv.w;
        }
        __syncthreads();
    }
    float* out = bz ? out1 : out0;
    #pragma unroll
    for (int i = 0; i < 2; i++) {
        int row = bm * 32 + ty * 2 + i;
        if (row >= M) continue;
        #pragma unroll
        for (int j = 0; j < 4; j++) {
            int col = bn * 64 + tx * 4 + j;
            if (col < AA) out[(size_t)row * AA + col] = acc[i][j];
        }
    }
}

// -------- prologue: att1 = part0 + part1 + bias --------
__global__ __launch_bounds__(256) void k_att1red(float* __restrict__ att1,
    const float* __restrict__ part, const float* __restrict__ bias) {
    size_t row = blockIdx.x;
    for (int c = threadIdx.x; c < AA; c += 256)
        att1[row * AA + c] += part[row * AA + c] + bias[c];
}

// -------- E2 body: reduce pE + b_fc -> preds; packed-u64 atomic argmax --------
__device__ __forceinline__ void e2_body(int bx, const float* __restrict__ pE,
    const float* __restrict__ bfc, float* __restrict__ preds,
    unsigned long long* __restrict__ g_arg, int t) {
    __shared__ float lg[128][8];
    int tid = threadIdx.x;
    int base = bx * 128;
    for (int idx = tid; idx < 1024; idx += 256) {
        int b = idx >> 7, cl = idx & 127;
        int col = base + cl;
        float s = -3.4e38f;
        if (col < VV) {
            s = bfc[col];
            #pragma unroll
            for (int kc = 0; kc < KSE; kc++)
                s += pE[((size_t)kc * 8 + b) * VV + col];
            preds[((size_t)b * NSTEP + t) * VV + col] = s;
        }
        lg[cl][b] = s;
    }
    __syncthreads();
    int b = tid >> 5, l = tid & 31;
    float bv = -3.4e38f; int bi = 0x7fffffff;
    for (int cl = l; cl < 128; cl += 32) {
        float v = lg[cl][b];
        int gi = base + cl;
        if (v > bv || (v == bv && gi < bi)) { bv = v; bi = gi; }
    }
    #pragma unroll
    for (int off = 16; off; off >>= 1) {
        float ov = __shfl_down(bv, off, 32);
        int   oi = __shfl_down(bi, off, 32);
        if (ov > bv || (ov == bv && oi < bi)) { bv = ov; bi = oi; }
    }
    if (l == 0 && bi < VV) {
        unsigned fb = __float_as_uint(bv);
        fb = (fb & 0x80000000u) ? ~fb : (fb | 0x80000000u);
        unsigned long long key = ((unsigned long long)fb << 32)
                               | (unsigned long long)(0xFFFFFFFFu - (unsigned)bi);
        atomicMax(&g_arg[t * 8 + b], key);
    }
}

// -------- fused: B(t) energies [0..391] || E2(t-1) [392..626] --------
__global__ __launch_bounds__(256) void k_stepBE2(const float* __restrict__ pA,
    const float* __restrict__ bda, const float* __restrict__ att1,
    const float* __restrict__ Wf, float* __restrict__ ebuf,
    const float* __restrict__ pE, const float* __restrict__ bfc,
    float* __restrict__ preds, unsigned long long* __restrict__ g_arg, int t) {
    int bx = blockIdx.x;
    int tid = threadIdx.x, lane = tid & 63, w = tid >> 6;
    if (bx >= NBB) {
        if (t > 0) e2_body(bx - NBB, pE, bfc, preds, g_arg, t - 1);
        return;
    }
    int b  = bx / 49;
    int p0 = (bx % 49) * 4;
    __shared__ float a2[AA];
    __shared__ float wf[AA];
    for (int i = tid; i < AA; i += 256) {
        float s = bda[i];
        #pragma unroll
        for (int kc = 0; kc < KSA; kc++) s += pA[((size_t)kc * 8 + b) * NA + i];
        a2[i] = s;
        wf[i] = Wf[i];
    }
    __syncthreads();
    int p = p0 + w;
    const float* ap = att1 + (size_t)(b * PP + p) * AA;
    float s = 0.f;
    for (int f4 = lane; f4 < 175; f4 += 64) {
        float4 av = *(const float4*)(ap + f4 * 4);
        float4 tv = *(const float4*)&a2[f4 * 4];
        float4 wv = *(const float4*)&wf[f4 * 4];
        s += fmaxf(av.x + tv.x, 0.f) * wv.x + fmaxf(av.y + tv.y, 0.f) * wv.y
           + fmaxf(av.z + tv.z, 0.f) * wv.z + fmaxf(av.w + tv.w, 0.f) * wv.w;
    }
    #pragma unroll
    for (int off = 32; off; off >>= 1) s += __shfl_down(s, off, 64);
    if (lane == 0) ebuf[b * PP + p] = s;
}

// -------- step C: 256 blocks (b x 32 d-chunks); redundant softmax; awe ----
__global__ __launch_bounds__(256) void k_stepC(const float* __restrict__ enc,
    const float* __restrict__ pA, const float* __restrict__ bfb,
    const float* __restrict__ ebuf, float* __restrict__ awe,
    float* __restrict__ oalpha, int t) {
    int b = blockIdx.x >> 5, dc = blockIdx.x & 31;
    __shared__ float s_al[PP];
    __shared__ float s_gate[64];
    __shared__ float s_red[4][64];
    __shared__ float s_rb[8];
    int tid = threadIdx.x, lane = tid & 63, w = tid >> 6;
    float v = (tid < PP) ? ebuf[b * PP + tid] : -3.4e38f;
    float m = v;
    #pragma unroll
    for (int off = 32; off; off >>= 1) m = fmaxf(m, __shfl_down(m, off, 64));
    if (lane == 0) s_rb[w] = m;
    __syncthreads();
    m = fmaxf(fmaxf(s_rb[0], s_rb[1]), fmaxf(s_rb[2], s_rb[3]));
    float ex = (tid < PP) ? expf(v - m) : 0.f;
    float s2 = ex;
    #pragma unroll
    for (int off = 32; off; off >>= 1) s2 += __shfl_down(s2, off, 64);
    if (lane == 0) s_rb[4 + w] = s2;
    __syncthreads();
    float den = s_rb[4] + s_rb[5] + s_rb[6] + s_rb[7];
    if (tid < PP) {
        float al = ex / den;
        s_al[tid] = al;
        if (dc == 0) oalpha[((size_t)b * NSTEP + t) * PP + tid] = al;
    }
    if (tid < 64) {
        int d = dc * 64 + tid;
        float g = bfb[d];
        #pragma unroll
        for (int kc = 0; kc < KSA; kc++) g += pA[((size_t)kc * 8 + b) * NA + AA + d];
        s_gate[tid] = sigm(g);
    }
    __syncthreads();
    int col = dc * 64 + lane;
    const float* ep = enc + ((size_t)b * PP + w * 49) * DD + col;
    float s = 0.f;
    #pragma unroll 7
    for (int p = 0; p < 49; ++p) {
        s += s_al[w * 49 + p] * ep[0];
        ep += DD;
    }
    s_red[w][lane] = s;
    __syncthreads();
    if (tid < 64) {
        float tot = s_red[0][tid] + s_red[1][tid] + s_red[2][tid] + s_red[3][tid];
        awe[b * DD + dc * 64 + tid] = s_gate[tid] * tot;
    }
}

// -------- step D1: decode prev from g_arg; pD[kc][b][col] partials --------
__global__ __launch_bounds__(256) void k_stepD1(const float* __restrict__ emb,
    const float* __restrict__ awe, const float* __restrict__ h,
    const float* __restrict__ Wih, const float* __restrict__ Whh,
    const unsigned long long* __restrict__ g_arg, float* __restrict__ pD, int t) {
    __shared__ float s_X[KRD * 8];
    __shared__ float s_red[4 * 64 * 33];
    __shared__ int s_prev[8];
    int tid = threadIdx.x;
    int cb = blockIdx.x % NCBD, kc = blockIdx.x / NCBD;
    int k0 = kc * KRD;
    int kr = min(KRD, KD - k0);
    if (tid < 8) {
        if (t == 0) s_prev[tid] = 1;
        else {
            unsigned long long key = g_arg[(t - 1) * 8 + tid];
            s_prev[tid] = (int)(0xFFFFFFFFu - (unsigned)(key & 0xFFFFFFFFull));
        }
    }
    __syncthreads();
    for (int i = tid; i < kr * 8; i += 256) {
        int k = i >> 3, b = i & 7;
        int kg = k0 + k;
        float x;
        if (kg < EE)            x = emb[(size_t)s_prev[b] * EE + kg];
        else if (kg < EE + DD)  x = awe[b * DD + (kg - EE)];
        else                    x = h[b * HH + (kg - EE - DD)];
        s_X[k * 8 + b] = x;
    }
    __syncthreads();
    int lane = tid & 63, w = tid >> 6;
    int ka = (w * kr) >> 2, kb2 = ((w + 1) * kr) >> 2;
    int c0 = cb * 256 + lane * 4;
    float acc[8][4] = {};
    if (c0 < G4) {
        #pragma unroll 2
        for (int k = ka; k < kb2; ++k) {
            int kg = k0 + k;
            const float* wp = (kg < EE + DD)
                ? (Wih + (size_t)kg * G4 + c0)
                : (Whh + (size_t)(kg - EE - DD) * G4 + c0);
            float4 wv = *(const float4*)wp;
            float4 xa = *(const float4*)&s_X[k * 8];
            float4 xb = *(const float4*)&s_X[k * 8 + 4];
            float xv[8] = {xa.x, xa.y, xa.z, xa.w, xb.x, xb.y, xb.z, xb.w};
            #pragma unroll
            for (int b = 0; b < 8; b++) {
                acc[b][0] += xv[b] * wv.x; acc[b][1] += xv[b] * wv.y;
                acc[b][2] += xv[b] * wv.z; acc[b][3] += xv[b] * wv.w;
            }
        }
    }
    float* rr = &s_red[(w * 64 + lane) * 33];
    #pragma unroll
    for (int b = 0; b < 8; b++)
        #pragma unroll
        for (int cc = 0; cc < 4; cc++) rr[cc * 8 + b] = acc[b][cc];
    __syncthreads();
    for (int idx = tid; idx < 2048; idx += 256) {
        int b = idx >> 8, cl = idx & 255;
        int gc = cb * 256 + cl;
        if (gc < G4) {
            int ln = cl >> 2, cc = cl & 3;
            float s = s_red[(0 * 64 + ln) * 33 + cc * 8 + b]
                    + s_red[(1 * 64 + ln) * 33 + cc * 8 + b]
                    + s_red[(2 * 64 + ln) * 33 + cc * 8 + b]
                    + s_red[(3 * 64 + ln) * 33 + cc * 8 + b];
            pD[((size_t)kc * 8 + b) * G4 + gc] = s;
        }
    }
}

// -------- step D2: reduce pD (48 chunks) + biases, LSTM cell --------
__global__ __launch_bounds__(256) void k_stepD2(const float* __restrict__ pD,
    const float* __restrict__ bih, const float* __restrict__ bhh,
    float* __restrict__ c, float* __restrict__ h) {
    __shared__ float sd[4][64][4];
    int tid = threadIdx.x;
    int p = tid & 63, kcg = tid >> 6;
    int oid = blockIdx.x * 64 + p;
    float g0 = 0.f, g1 = 0.f, g2 = 0.f, g3 = 0.f;
    if (oid < BQ * HH) {
        int b = oid / HH, j = oid % HH;
        #pragma unroll
        for (int u = 0; u < 12; ++u) {
            const float* base = pD + ((size_t)(kcg * 12 + u) * 8 + b) * G4;
            g0 += base[j];          g1 += base[HH + j];
            g2 += base[2 * HH + j]; g3 += base[3 * HH + j];
        }
    }
    sd[kcg][p][0] = g0; sd[kcg][p][1] = g1;
    sd[kcg][p][2] = g2; sd[kcg][p][3] = g3;
    __syncthreads();
    if (tid < 64) {
        int oid2 = blockIdx.x * 64 + tid;
        if (oid2 < BQ * HH) {
            int b = oid2 / HH, j = oid2 % HH;
            float s0 = sd[0][tid][0] + sd[1][tid][0] + sd[2][tid][0] + sd[3][tid][0]
                     + bih[j] + bhh[j];
            float s1 = sd[0][tid][1] + sd[1][tid][1] + sd[2][tid][1] + sd[3][tid][1]
                     + bih[HH + j] + bhh[HH + j];
            float s2 = sd[0][tid][2] + sd[1][tid][2] + sd[2][tid][2] + sd[3][tid][2]
                     + bih[2 * HH + j] + bhh[2 * HH + j];
            float s3 = sd[0][tid][3] + sd[1][tid][3] + sd[2][tid][3] + sd[3][tid][3]
                     + bih[3 * HH + j] + bhh[3 * HH + j];
            float ig = sigm(s0), fg = sigm(s1), gg = tanhf(s2), og = sigm(s3);
            float cn = fg * c[b * HH + j] + ig * gg;
            c[b * HH + j] = cn;
            h[b * HH + j] = og * tanhf(cn);
        }
    }
}

// -------- fused: E1(t) [blocks 0..707] || A(t+1) [blocks 708..795] --------
__global__ __launch_bounds__(256) void k_stepEA(const float* __restrict__ h,
    const float* __restrict__ Wfc, float* __restrict__ pE,
    const float* __restrict__ Wda, const float* __restrict__ Wfb,
    float* __restrict__ pA, int only_a) {
    __shared__ float s_X[KRE * 8];
    __shared__ float s_red[4 * 64 * 33];
    int tid = threadIdx.x;
    int bx = blockIdx.x;
    int lane = tid & 63, w = tid >> 6;
    bool doA; int abid = 0;
    if (only_a)                { doA = true;  abid = bx; }
    else if (bx >= NCBE * KSE) { doA = true;  abid = bx - NCBE * KSE; }
    else                       { doA = false; }

    if (doA) {
        int cb = abid % NCBA, kc = abid / NCBA;
        int k0 = kc * KRA;
        int kr = min(KRA, AA - k0);
        for (int i = tid; i < kr * 8; i += 256) {
            int k = i >> 3, b = i & 7;
            s_X[k * 8 + b] = h[b * HH + k0 + k];
        }
        __syncthreads();
        int ka = (w * kr) >> 2, kb = ((w + 1) * kr) >> 2;
        int c0 = cb * 256 + lane * 4;
        float acc[8][4] = {};
        if (c0 < NA) {
            const float* W; int col, ld;
            if (c0 < AA) { W = Wda; col = c0;      ld = AA; }
            else         { W = Wfb; col = c0 - AA; ld = DD; }
            const float* wp = W + (size_t)(k0 + ka) * ld + col;
            #pragma unroll 2
            for (int k = ka; k < kb; ++k) {
                float4 wv = *(const float4*)wp; wp += ld;
                float4 xa = *(const float4*)&s_X[k * 8];
                float4 xb = *(const float4*)&s_X[k * 8 + 4];
                float xv[8] = {xa.x, xa.y, xa.z, xa.w, xb.x, xb.y, xb.z, xb.w};
                #pragma unroll
                for (int b = 0; b < 8; b++) {
                    acc[b][0] += xv[b] * wv.x; acc[b][1] += xv[b] * wv.y;
                    acc[b][2] += xv[b] * wv.z; acc[b][3] += xv[b] * wv.w;
                }
            }
        }
        float* rr = &s_red[(w * 64 + lane) * 33];
        #pragma unroll
        for (int b = 0; b < 8; b++)
            #pragma unroll
            for (int cc = 0; cc < 4; cc++) rr[cc * 8 + b] = acc[b][cc];
        __syncthreads();
        for (int idx = tid; idx < 2048; idx += 256) {
            int b = idx >> 8, cl = idx & 255;
            int gc = cb * 256 + cl;
            if (gc < NA) {
                int ln = cl >> 2, cc = cl & 3;
                float s = s_red[(0 * 64 + ln) * 33 + cc * 8 + b]
                        + s_red[(1 * 64 + ln) * 33 + cc * 8 + b]
                        + s_red[(2 * 64 + ln) * 33 + cc * 8 + b]
                        + s_red[(3 * 64 + ln) * 33 + cc * 8 + b];
                pA[((size_t)kc * 8 + b) * NA + gc] = s;
            }
        }
    } else {
        int cb = bx % NCBE, kc = bx / NCBE;
        int k0 = kc * KRE;
        int kr = min(KRE, AA - k0);
        for (int i = tid; i < kr * 8; i += 256) {
            int k = i >> 3, b = i & 7;
            s_X[k * 8 + b] = h[b * HH + k0 + k];
        }
        __syncthreads();
        int ka = (w * kr) >> 2, kb = ((w + 1) * kr) >> 2;
        int c0 = cb * 256 + lane * 4;
        float acc[8][4] = {};
        if (c0 < VV) {
            const float* wp = Wfc + (size_t)(k0 + ka) * VV + c0;
            #pragma unroll 2
            for (int k = ka; k < kb; ++k) {
                float4 wv = *(const float4*)wp; wp += VV;
                float4 xa = *(const float4*)&s_X[k * 8];
                float4 xb = *(const float4*)&s_X[k * 8 + 4];
                float xv[8] = {xa.x, xa.y, xa.z, xa.w, xb.x, xb.y, xb.z, xb.w};
                #pragma unroll
                for (int b = 0; b < 8; b++) {
                    acc[b][0] += xv[b] * wv.x; acc[b][1] += xv[b] * wv.y;
                    acc[b][2] += xv[b] * wv.z; acc[b][3] += xv[b] * wv.w;
                }
            }
        }
        float* rr = &s_red[(w * 64 + lane) * 33];
        #pragma unroll
        for (int b = 0; b < 8; b++)
            #pragma unroll
            for (int cc = 0; cc < 4; cc++) rr[cc * 8 + b] = acc[b][cc];
        __syncthreads();
        for (int idx = tid; idx < 2048; idx += 256) {
            int b = idx >> 8, cl = idx & 255;
            int gc = cb * 256 + cl;
            if (gc < VV) {
                int ln = cl >> 2, cc = cl & 3;
                float s = s_red[(0 * 64 + ln) * 33 + cc * 8 + b]
                        + s_red[(1 * 64 + ln) * 33 + cc * 8 + b]
                        + s_red[(2 * 64 + ln) * 33 + cc * 8 + b]
                        + s_red[(3 * 64 + ln) * 33 + cc * 8 + b];
                pE[((size_t)kc * 8 + b) * VV + gc] = s;
            }
        }
    }
}

// -------- standalone E2 (epilogue, t = NSTEP-1) --------
__global__ __launch_bounds__(256) void k_stepE2(const float* __restrict__ pE,
    const float* __restrict__ bfc, float* __restrict__ preds,
    unsigned long long* __restrict__ g_arg, int t) {
    e2_body(blockIdx.x, pE, bfc, preds, g_arg, t);
}

extern "C" void kernel_launch(void* const* d_in, const int* in_sizes, int n_in,
                              void* d_out, int out_size, void* d_ws, size_t ws_size,
                              hipStream_t stream) {
    (void)in_sizes; (void)n_in; (void)out_size; (void)ws_size;
    const float* enc   = (const float*)d_in[0];
    const float* emb   = (const float*)d_in[2];
    const float* Wea   = (const float*)d_in[3];
    const float* bea   = (const float*)d_in[4];
    const float* Wda   = (const float*)d_in[5];
    const float* bda   = (const float*)d_in[6];
    const float* Wfull = (const float*)d_in[7];
    // d_in[8] = b_full (softmax-invariant, unused)
    const float* Wih   = (const float*)d_in[9];
    const float* bih   = (const float*)d_in[10];
    const float* Whh   = (const float*)d_in[11];
    const float* bhh   = (const float*)d_in[12];
    const float* Winh  = (const float*)d_in[13];
    const float* binh  = (const float*)d_in[14];
    const float* Winc  = (const float*)d_in[15];
    const float* binc  = (const float*)d_in[16];
    const float* Wfb   = (const float*)d_in[17];
    const float* bfb   = (const float*)d_in[18];
    const float* Wfc   = (const float*)d_in[19];
    const float* bfc   = (const float*)d_in[20];

    float* preds  = (float*)d_out;
    float* oalpha = preds + (size_t)BQ * NSTEP * VV;

    unsigned long long* g_arg = (unsigned long long*)d_ws;   // 240 u64
    float* ws = (float*)d_ws + 480;
    float* att1 = ws; ws += (size_t)BQ * PP * AA;    // 1,097,600
    float* pA   = ws; ws += (size_t)KSA * 8 * NA;    //   175,872
    float* pDE  = ws; ws += (size_t)KSE * 8 * VV;    // 1,440,000 (att1 z-partial, pD, pE)
    float* mean = ws; ws += BQ * DD;
    float* hbuf = ws; ws += BQ * HH;
    float* cbuf = ws; ws += BQ * HH;
    float* ebuf = ws; ws += BQ * PP;
    float* awe  = ws; ws += BQ * DD;

    k_mean<<<64, 256, 0, stream>>>(enc, mean, g_arg);
    k_init_hc<<<22, 256, 0, stream>>>(mean, Winh, binh, Winc, binc, hbuf, cbuf);
    k_att1<<<dim3(49, 11, 2), 256, 0, stream>>>(enc, Wea, att1, pDE);
    k_att1red<<<BQ * PP, 256, 0, stream>>>(att1, pDE, bea);
    // A(0) from h0
    k_stepEA<<<NCBA * KSA, 256, 0, stream>>>(hbuf, Wfc, pDE, Wda, Wfb, pA, 1);

    for (int t = 0; t < NSTEP; t++) {
        k_stepBE2<<<NBB + NB2, 256, 0, stream>>>(pA, bda, att1, Wfull, ebuf,
                                                 pDE, bfc, preds, g_arg, t);
        k_stepC<<<256, 256, 0, stream>>>(enc, pA, bfb, ebuf, awe, oalpha, t);
        k_stepD1<<<NCBD * KSD, 256, 0, stream>>>(emb, awe, hbuf, Wih, Whh,
                                                 g_arg, pDE, t);
        k_stepD2<<<88, 256, 0, stream>>>(pDE, bih, bhh, cbuf, hbuf);
        k_stepEA<<<NCBE * KSE + NCBA * KSA, 256, 0, stream>>>(hbuf, Wfc, pDE,
                                                              Wda, Wfb, pA, 0);
    }
    k_stepE2<<<NB2, 256, 0, stream>>>(pDE, bfc, preds, g_arg, NSTEP - 1);
}

// Round 9
// 1720.720 us; speedup vs baseline: 1.0407x; 1.0407x over previous
//
#include <hip/hip_runtime.h>
#include <math.h>

#define BQ 8
#define PP 196
#define DD 2048
#define AA 700
#define HH 700
#define EE 700
#define VV 30000
#define NSTEP 30
#define G4 2800
#define NA 2748    // A cols: att2(700) + gLin(2048)
#define KD 3448    // D1 virtual K: emb(700) + awe(2048) + h(700)

#define KSA 8
#define KRA 88
#define NCBA 11

#define KSD 48
#define KRD 72
#define NCBD 11

#define KSE 6
#define KRE 117
#define NCBE 118
#define NB2 235    // E2 blocks
#define NBB 392    // B blocks

__device__ __forceinline__ float sigm(float x) { return 1.f / (1.f + expf(-x)); }

// -------- prologue: mean over pixels; also zero g_arg --------
__global__ __launch_bounds__(256) void k_mean(const float* __restrict__ enc,
                                              float* __restrict__ mean,
                                              unsigned long long* __restrict__ g_arg) {
    if (blockIdx.x == 0 && threadIdx.x < NSTEP * 8) g_arg[threadIdx.x] = 0ULL;
    int b = blockIdx.x >> 3;
    int d = ((blockIdx.x & 7) << 8) + threadIdx.x;
    const float* p = enc + (size_t)b * PP * DD + d;
    float s = 0.f;
    for (int i = 0; i < PP; i++) s += p[(size_t)i * DD];
    mean[b * DD + d] = s * (1.0f / PP);
}

// -------- prologue: h0 / c0 --------
__global__ __launch_bounds__(256) void k_init_hc(const float* __restrict__ mean,
    const float* __restrict__ Wh, const float* __restrict__ bh,
    const float* __restrict__ Wc, const float* __restrict__ bc,
    float* __restrict__ h, float* __restrict__ c) {
    __shared__ float X[BQ][DD];
    __shared__ float red[4][64][BQ];
    int tid = threadIdx.x;
    for (int i = tid; i < BQ * DD; i += 256) X[i / DD][i % DD] = mean[i];
    __syncthreads();
    int j = blockIdx.x * 64 + (tid & 63);
    int kq = tid >> 6;
    float acc[BQ];
    #pragma unroll
    for (int b = 0; b < BQ; b++) acc[b] = 0.f;
    if (j < 2 * HH) {
        bool isH = j < HH;
        int col = isH ? j : j - HH;
        const float* wp = (isH ? Wh : Wc) + (size_t)(kq * 512) * HH + col;
        for (int k = kq * 512; k < kq * 512 + 512; k++) {
            float wv = *wp; wp += HH;
            #pragma unroll
            for (int b = 0; b < BQ; b++) acc[b] += X[b][k] * wv;
        }
    }
    #pragma unroll
    for (int b = 0; b < BQ; b++) red[kq][tid & 63][b] = acc[b];
    __syncthreads();
    for (int idx = tid; idx < 512; idx += 256) {
        int jj = idx >> 3, b = idx & 7;
        int jg = blockIdx.x * 64 + jj;
        if (jg >= 2 * HH) continue;
        float s = red[0][jj][b] + red[1][jj][b] + red[2][jj][b] + red[3][jj][b];
        bool isH = jg < HH;
        int col = isH ? jg : jg - HH;
        s += isH ? bh[col] : bc[col];
        (isH ? h : c)[b * HH + col] = s;
    }
}

// -------- prologue: att1 partials, 64x64 tile (r4-verified body), k split 4 ----
__global__ __launch_bounds__(256) void k_att1(const float* __restrict__ Aenc,
    const float* __restrict__ W, float* __restrict__ out0,
    float* __restrict__ out1, float* __restrict__ out2,
    float* __restrict__ out3) {
    const int M = BQ * PP; // 1568
    __shared__ float As[16][68];
    __shared__ float Bs[16][68];
    int bm = blockIdx.x, bn = blockIdx.y, bz = blockIdx.z;
    int tid = threadIdx.x;
    int tx = tid & 15, ty = tid >> 4;
    float acc[4][4] = {};
    int kbeg = bz * 512, kend = kbeg + 512;
    for (int kt = kbeg; kt < kend; kt += 16) {
        {
            int row = tid >> 2, k4 = (tid & 3) * 4;
            int grow = bm * 64 + row;
            float4 v = make_float4(0.f, 0.f, 0.f, 0.f);
            if (grow < M) v = *(const float4*)&Aenc[(size_t)grow * DD + kt + k4];
            As[k4 + 0][row] = v.x; As[k4 + 1][row] = v.y;
            As[k4 + 2][row] = v.z; As[k4 + 3][row] = v.w;
        }
        {
            int rk = tid >> 4, n4 = (tid & 15) * 4;
            int col = bn * 64 + n4;
            float4 wv = make_float4(0.f, 0.f, 0.f, 0.f);
            if (col < AA) wv = *(const float4*)&W[(size_t)(kt + rk) * AA + col];
            *(float4*)&Bs[rk][n4] = wv;
        }
        __syncthreads();
        #pragma unroll
        for (int k = 0; k < 16; k++) {
            float4 a  = *(const float4*)&As[k][ty * 4];
            float4 bv = *(const float4*)&Bs[k][tx * 4];
            float av[4] = {a.x, a.y, a.z, a.w};
            float bb[4] = {bv.x, bv.y, bv.z, bv.w};
            #pragma unroll
            for (int i = 0; i < 4; i++)
                #pragma unroll
                for (int j = 0; j < 4; j++) acc[i][j] += av[i] * bb[j];
        }
        __syncthreads();
    }
    float* out = (bz == 0) ? out0 : (bz == 1) ? out1 : (bz == 2) ? out2 : out3;
    for (int i = 0; i < 4; i++) {
        int row = bm * 64 + ty * 4 + i;
        if (row >= M) continue;
        for (int j = 0; j < 4; j++) {
            int col = bn * 64 + tx * 4 + j;
            if (col < AA) out[(size_t)row * AA + col] = acc[i][j];
        }
    }
}

// -------- prologue: att1 = z0 + z1 + z2 + z3 + bias --------
__global__ __launch_bounds__(256) void k_att1red(float* __restrict__ att1,
    const float* __restrict__ p1, const float* __restrict__ p2,
    const float* __restrict__ p3, const float* __restrict__ bias) {
    size_t row = blockIdx.x;
    for (int c = threadIdx.x; c < AA; c += 256) {
        size_t i = row * AA + c;
        att1[i] = att1[i] + p1[i] + p2[i] + p3[i] + bias[c];
    }
}

// -------- E2 body: reduce pE + b_fc -> preds; packed-u64 atomic argmax --------
__device__ __forceinline__ void e2_body(int bx, const float* __restrict__ pE,
    const float* __restrict__ bfc, float* __restrict__ preds,
    unsigned long long* __restrict__ g_arg, int t) {
    __shared__ float lg[128][8];
    int tid = threadIdx.x;
    int base = bx * 128;
    for (int idx = tid; idx < 1024; idx += 256) {
        int b = idx >> 7, cl = idx & 127;
        int col = base + cl;
        float s = -3.4e38f;
        if (col < VV) {
            s = bfc[col];
            #pragma unroll
            for (int kc = 0; kc < KSE; kc++)
                s += pE[((size_t)kc * 8 + b) * VV + col];
            preds[((size_t)b * NSTEP + t) * VV + col] = s;
        }
        lg[cl][b] = s;
    }
    __syncthreads();
    int b = tid >> 5, l = tid & 31;
    float bv = -3.4e38f; int bi = 0x7fffffff;
    for (int cl = l; cl < 128; cl += 32) {
        float v = lg[cl][b];
        int gi = base + cl;
        if (v > bv || (v == bv && gi < bi)) { bv = v; bi = gi; }
    }
    #pragma unroll
    for (int off = 16; off; off >>= 1) {
        float ov = __shfl_down(bv, off, 32);
        int   oi = __shfl_down(bi, off, 32);
        if (ov > bv || (ov == bv && oi < bi)) { bv = ov; bi = oi; }
    }
    if (l == 0 && bi < VV) {
        unsigned fb = __float_as_uint(bv);
        fb = (fb & 0x80000000u) ? ~fb : (fb | 0x80000000u);
        unsigned long long key = ((unsigned long long)fb << 32)
                               | (unsigned long long)(0xFFFFFFFFu - (unsigned)bi);
        atomicMax(&g_arg[t * 8 + b], key);
    }
}

// -------- fused: B(t) energies [0..391] || E2(t-1) [392..626] --------
__global__ __launch_bounds__(256) void k_stepBE2(const float* __restrict__ pA,
    const float* __restrict__ bda, const float* __restrict__ att1,
    const float* __restrict__ Wf, float* __restrict__ ebuf,
    const float* __restrict__ pE, const float* __restrict__ bfc,
    float* __restrict__ preds, unsigned long long* __restrict__ g_arg, int t) {
    int bx = blockIdx.x;
    int tid = threadIdx.x, lane = tid & 63, w = tid >> 6;
    if (bx >= NBB) {
        if (t > 0) e2_body(bx - NBB, pE, bfc, preds, g_arg, t - 1);
        return;
    }
    int b  = bx / 49;
    int p0 = (bx % 49) * 4;
    __shared__ float a2[AA];
    __shared__ float wf[AA];
    for (int i = tid; i < AA; i += 256) {
        float s = bda[i];
        #pragma unroll
        for (int kc = 0; kc < KSA; kc++) s += pA[((size_t)kc * 8 + b) * NA + i];
        a2[i] = s;
        wf[i] = Wf[i];
    }
    __syncthreads();
    int p = p0 + w;
    const float* ap = att1 + (size_t)(b * PP + p) * AA;
    float s = 0.f;
    for (int f4 = lane; f4 < 175; f4 += 64) {
        float4 av = *(const float4*)(ap + f4 * 4);
        float4 tv = *(const float4*)&a2[f4 * 4];
        float4 wv = *(const float4*)&wf[f4 * 4];
        s += fmaxf(av.x + tv.x, 0.f) * wv.x + fmaxf(av.y + tv.y, 0.f) * wv.y
           + fmaxf(av.z + tv.z, 0.f) * wv.z + fmaxf(av.w + tv.w, 0.f) * wv.w;
    }
    #pragma unroll
    for (int off = 32; off; off >>= 1) s += __shfl_down(s, off, 64);
    if (lane == 0) ebuf[b * PP + p] = s;
}

// -------- step C: 256 blocks (b x 32 d-chunks); redundant softmax; awe ----
__global__ __launch_bounds__(256) void k_stepC(const float* __restrict__ enc,
    const float* __restrict__ pA, const float* __restrict__ bfb,
    const float* __restrict__ ebuf, float* __restrict__ awe,
    float* __restrict__ oalpha, int t) {
    int b = blockIdx.x >> 5, dc = blockIdx.x & 31;
    __shared__ float s_al[PP];
    __shared__ float s_gate[64];
    __shared__ float s_red[4][64];
    __shared__ float s_rb[8];
    int tid = threadIdx.x, lane = tid & 63, w = tid >> 6;
    float v = (tid < PP) ? ebuf[b * PP + tid] : -3.4e38f;
    float m = v;
    #pragma unroll
    for (int off = 32; off; off >>= 1) m = fmaxf(m, __shfl_down(m, off, 64));
    if (lane == 0) s_rb[w] = m;
    __syncthreads();
    m = fmaxf(fmaxf(s_rb[0], s_rb[1]), fmaxf(s_rb[2], s_rb[3]));
    float ex = (tid < PP) ? expf(v - m) : 0.f;
    float s2 = ex;
    #pragma unroll
    for (int off = 32; off; off >>= 1) s2 += __shfl_down(s2, off, 64);
    if (lane == 0) s_rb[4 + w] = s2;
    __syncthreads();
    float den = s_rb[4] + s_rb[5] + s_rb[6] + s_rb[7];
    if (tid < PP) {
        float al = ex / den;
        s_al[tid] = al;
        if (dc == 0) oalpha[((size_t)b * NSTEP + t) * PP + tid] = al;
    }
    if (tid < 64) {
        int d = dc * 64 + tid;
        float g = bfb[d];
        #pragma unroll
        for (int kc = 0; kc < KSA; kc++) g += pA[((size_t)kc * 8 + b) * NA + AA + d];
        s_gate[tid] = sigm(g);
    }
    __syncthreads();
    int col = dc * 64 + lane;
    const float* ep = enc + ((size_t)b * PP + w * 49) * DD + col;
    float s = 0.f;
    #pragma unroll 7
    for (int p = 0; p < 49; ++p) {
        s += s_al[w * 49 + p] * ep[0];
        ep += DD;
    }
    s_red[w][lane] = s;
    __syncthreads();
    if (tid < 64) {
        float tot = s_red[0][tid] + s_red[1][tid] + s_red[2][tid] + s_red[3][tid];
        awe[b * DD + dc * 64 + tid] = s_gate[tid] * tot;
    }
}

// -------- step D1: decode prev from g_arg; pD[kc][b][col] partials --------
__global__ __launch_bounds__(256) void k_stepD1(const float* __restrict__ emb,
    const float* __restrict__ awe, const float* __restrict__ h,
    const float* __restrict__ Wih, const float* __restrict__ Whh,
    const unsigned long long* __restrict__ g_arg, float* __restrict__ pD, int t) {
    __shared__ float s_X[KRD * 8];
    __shared__ float s_red[4 * 64 * 33];
    __shared__ int s_prev[8];
    int tid = threadIdx.x;
    int cb = blockIdx.x % NCBD, kc = blockIdx.x / NCBD;
    int k0 = kc * KRD;
    int kr = min(KRD, KD - k0);
    if (tid < 8) {
        if (t == 0) s_prev[tid] = 1;
        else {
            unsigned long long key = g_arg[(t - 1) * 8 + tid];
            s_prev[tid] = (int)(0xFFFFFFFFu - (unsigned)(key & 0xFFFFFFFFull));
        }
    }
    __syncthreads();
    for (int i = tid; i < kr * 8; i += 256) {
        int k = i >> 3, b = i & 7;
        int kg = k0 + k;
        float x;
        if (kg < EE)            x = emb[(size_t)s_prev[b] * EE + kg];
        else if (kg < EE + DD)  x = awe[b * DD + (kg - EE)];
        else                    x = h[b * HH + (kg - EE - DD)];
        s_X[k * 8 + b] = x;
    }
    __syncthreads();
    int lane = tid & 63, w = tid >> 6;
    int ka = (w * kr) >> 2, kb2 = ((w + 1) * kr) >> 2;
    int c0 = cb * 256 + lane * 4;
    float acc[8][4] = {};
    if (c0 < G4) {
        #pragma unroll 2
        for (int k = ka; k < kb2; ++k) {
            int kg = k0 + k;
            const float* wp = (kg < EE + DD)
                ? (Wih + (size_t)kg * G4 + c0)
                : (Whh + (size_t)(kg - EE - DD) * G4 + c0);
            float4 wv = *(const float4*)wp;
            float4 xa = *(const float4*)&s_X[k * 8];
            float4 xb = *(const float4*)&s_X[k * 8 + 4];
            float xv[8] = {xa.x, xa.y, xa.z, xa.w, xb.x, xb.y, xb.z, xb.w};
            #pragma unroll
            for (int b = 0; b < 8; b++) {
                acc[b][0] += xv[b] * wv.x; acc[b][1] += xv[b] * wv.y;
                acc[b][2] += xv[b] * wv.z; acc[b][3] += xv[b] * wv.w;
            }
        }
    }
    float* rr = &s_red[(w * 64 + lane) * 33];
    #pragma unroll
    for (int b = 0; b < 8; b++)
        #pragma unroll
        for (int cc = 0; cc < 4; cc++) rr[cc * 8 + b] = acc[b][cc];
    __syncthreads();
    for (int idx = tid; idx < 2048; idx += 256) {
        int b = idx >> 8, cl = idx & 255;
        int gc = cb * 256 + cl;
        if (gc < G4) {
            int ln = cl >> 2, cc = cl & 3;
            float s = s_red[(0 * 64 + ln) * 33 + cc * 8 + b]
                    + s_red[(1 * 64 + ln) * 33 + cc * 8 + b]
                    + s_red[(2 * 64 + ln) * 33 + cc * 8 + b]
                    + s_red[(3 * 64 + ln) * 33 + cc * 8 + b];
            pD[((size_t)kc * 8 + b) * G4 + gc] = s;
        }
    }
}

// -------- step D2: reduce pD (48 chunks) + biases, LSTM cell --------
__global__ __launch_bounds__(256) void k_stepD2(const float* __restrict__ pD,
    const float* __restrict__ bih, const float* __restrict__ bhh,
    float* __restrict__ c, float* __restrict__ h) {
    __shared__ float sd[4][64][4];
    int tid = threadIdx.x;
    int p = tid & 63, kcg = tid >> 6;
    int oid = blockIdx.x * 64 + p;
    float g0 = 0.f, g1 = 0.f, g2 = 0.f, g3 = 0.f;
    if (oid < BQ * HH) {
        int b = oid / HH, j = oid % HH;
        #pragma unroll
        for (int u = 0; u < 12; ++u) {
            const float* base = pD + ((size_t)(kcg * 12 + u) * 8 + b) * G4;
            g0 += base[j];          g1 += base[HH + j];
            g2 += base[2 * HH + j]; g3 += base[3 * HH + j];
        }
    }
    sd[kcg][p][0] = g0; sd[kcg][p][1] = g1;
    sd[kcg][p][2] = g2; sd[kcg][p][3] = g3;
    __syncthreads();
    if (tid < 64) {
        int oid2 = blockIdx.x * 64 + tid;
        if (oid2 < BQ * HH) {
            int b = oid2 / HH, j = oid2 % HH;
            float s0 = sd[0][tid][0] + sd[1][tid][0] + sd[2][tid][0] + sd[3][tid][0]
                     + bih[j] + bhh[j];
            float s1 = sd[0][tid][1] + sd[1][tid][1] + sd[2][tid][1] + sd[3][tid][1]
                     + bih[HH + j] + bhh[HH + j];
            float s2 = sd[0][tid][2] + sd[1][tid][2] + sd[2][tid][2] + sd[3][tid][2]
                     + bih[2 * HH + j] + bhh[2 * HH + j];
            float s3 = sd[0][tid][3] + sd[1][tid][3] + sd[2][tid][3] + sd[3][tid][3]
                     + bih[3 * HH + j] + bhh[3 * HH + j];
            float ig = sigm(s0), fg = sigm(s1), gg = tanhf(s2), og = sigm(s3);
            float cn = fg * c[b * HH + j] + ig * gg;
            c[b * HH + j] = cn;
            h[b * HH + j] = og * tanhf(cn);
        }
    }
}

// -------- fused: E1(t) [blocks 0..707] || A(t+1) [blocks 708..795] --------
__global__ __launch_bounds__(256) void k_stepEA(const float* __restrict__ h,
    const float* __restrict__ Wfc, float* __restrict__ pE,
    const float* __restrict__ Wda, const float* __restrict__ Wfb,
    float* __restrict__ pA, int only_a) {
    __shared__ float s_X[KRE * 8];
    __shared__ float s_red[4 * 64 * 33];
    int tid = threadIdx.x;
    int bx = blockIdx.x;
    int lane = tid & 63, w = tid >> 6;
    bool doA; int abid = 0;
    if (only_a)                { doA = true;  abid = bx; }
    else if (bx >= NCBE * KSE) { doA = true;  abid = bx - NCBE * KSE; }
    else                       { doA = false; }

    if (doA) {
        int cb = abid % NCBA, kc = abid / NCBA;
        int k0 = kc * KRA;
        int kr = min(KRA, AA - k0);
        for (int i = tid; i < kr * 8; i += 256) {
            int k = i >> 3, b = i & 7;
            s_X[k * 8 + b] = h[b * HH + k0 + k];
        }
        __syncthreads();
        int ka = (w * kr) >> 2, kb = ((w + 1) * kr) >> 2;
        int c0 = cb * 256 + lane * 4;
        float acc[8][4] = {};
        if (c0 < NA) {
            const float* W; int col, ld;
            if (c0 < AA) { W = Wda; col = c0;      ld = AA; }
            else         { W = Wfb; col = c0 - AA; ld = DD; }
            const float* wp = W + (size_t)(k0 + ka) * ld + col;
            #pragma unroll 2
            for (int k = ka; k < kb; ++k) {
                float4 wv = *(const float4*)wp; wp += ld;
                float4 xa = *(const float4*)&s_X[k * 8];
                float4 xb = *(const float4*)&s_X[k * 8 + 4];
                float xv[8] = {xa.x, xa.y, xa.z, xa.w, xb.x, xb.y, xb.z, xb.w};
                #pragma unroll
                for (int b = 0; b < 8; b++) {
                    acc[b][0] += xv[b] * wv.x; acc[b][1] += xv[b] * wv.y;
                    acc[b][2] += xv[b] * wv.z; acc[b][3] += xv[b] * wv.w;
                }
            }
        }
        float* rr = &s_red[(w * 64 + lane) * 33];
        #pragma unroll
        for (int b = 0; b < 8; b++)
            #pragma unroll
            for (int cc = 0; cc < 4; cc++) rr[cc * 8 + b] = acc[b][cc];
        __syncthreads();
        for (int idx = tid; idx < 2048; idx += 256) {
            int b = idx >> 8, cl = idx & 255;
            int gc = cb * 256 + cl;
            if (gc < NA) {
                int ln = cl >> 2, cc = cl & 3;
                float s = s_red[(0 * 64 + ln) * 33 + cc * 8 + b]
                        + s_red[(1 * 64 + ln) * 33 + cc * 8 + b]
                        + s_red[(2 * 64 + ln) * 33 + cc * 8 + b]
                        + s_red[(3 * 64 + ln) * 33 + cc * 8 + b];
                pA[((size_t)kc * 8 + b) * NA + gc] = s;
            }
        }
    } else {
        int cb = bx % NCBE, kc = bx / NCBE;
        int k0 = kc * KRE;
        int kr = min(KRE, AA - k0);
        for (int i = tid; i < kr * 8; i += 256) {
            int k = i >> 3, b = i & 7;
            s_X[k * 8 + b] = h[b * HH + k0 + k];
        }
        __syncthreads();
        int ka = (w * kr) >> 2, kb = ((w + 1) * kr) >> 2;
        int c0 = cb * 256 + lane * 4;
        float acc[8][4] = {};
        if (c0 < VV) {
            const float* wp = Wfc + (size_t)(k0 + ka) * VV + c0;
            #pragma unroll 2
            for (int k = ka; k < kb; ++k) {
                float4 wv = *(const float4*)wp; wp += VV;
                float4 xa = *(const float4*)&s_X[k * 8];
                float4 xb = *(const float4*)&s_X[k * 8 + 4];
                float xv[8] = {xa.x, xa.y, xa.z, xa.w, xb.x, xb.y, xb.z, xb.w};
                #pragma unroll
                for (int b = 0; b < 8; b++) {
                    acc[b][0] += xv[b] * wv.x; acc[b][1] += xv[b] * wv.y;
                    acc[b][2] += xv[b] * wv.z; acc[b][3] += xv[b] * wv.w;
                }
            }
        }
        float* rr = &s_red[(w * 64 + lane) * 33];
        #pragma unroll
        for (int b = 0; b < 8; b++)
            #pragma unroll
            for (int cc = 0; cc < 4; cc++) rr[cc * 8 + b] = acc[b][cc];
        __syncthreads();
        for (int idx = tid; idx < 2048; idx += 256) {
            int b = idx >> 8, cl = idx & 255;
            int gc = cb * 256 + cl;
            if (gc < VV) {
                int ln = cl >> 2, cc = cl & 3;
                float s = s_red[(0 * 64 + ln) * 33 + cc * 8 + b]
                        + s_red[(1 * 64 + ln) * 33 + cc * 8 + b]
                        + s_red[(2 * 64 + ln) * 33 + cc * 8 + b]
                        + s_red[(3 * 64 + ln) * 33 + cc * 8 + b];
                pE[((size_t)kc * 8 + b) * VV + gc] = s;
            }
        }
    }
}

// -------- standalone E2 (epilogue, t = NSTEP-1) --------
__global__ __launch_bounds__(256) void k_stepE2(const float* __restrict__ pE,
    const float* __restrict__ bfc, float* __restrict__ preds,
    unsigned long long* __restrict__ g_arg, int t) {
    e2_body(blockIdx.x, pE, bfc, preds, g_arg, t);
}

extern "C" void kernel_launch(void* const* d_in, const int* in_sizes, int n_in,
                              void* d_out, int out_size, void* d_ws, size_t ws_size,
                              hipStream_t stream) {
    (void)in_sizes; (void)n_in; (void)out_size; (void)ws_size;
    const float* enc   = (const float*)d_in[0];
    const float* emb   = (const float*)d_in[2];
    const float* Wea   = (const float*)d_in[3];
    const float* bea   = (const float*)d_in[4];
    const float* Wda   = (const float*)d_in[5];
    const float* bda   = (const float*)d_in[6];
    const float* Wfull = (const float*)d_in[7];
    // d_in[8] = b_full (softmax-invariant, unused)
    const float* Wih   = (const float*)d_in[9];
    const float* bih   = (const float*)d_in[10];
    const float* Whh   = (const float*)d_in[11];
    const float* bhh   = (const float*)d_in[12];
    const float* Winh  = (const float*)d_in[13];
    const float* binh  = (const float*)d_in[14];
    const float* Winc  = (const float*)d_in[15];
    const float* binc  = (const float*)d_in[16];
    const float* Wfb   = (const float*)d_in[17];
    const float* bfb   = (const float*)d_in[18];
    const float* Wfc   = (const float*)d_in[19];
    const float* bfc   = (const float*)d_in[20];

    float* preds  = (float*)d_out;
    float* oalpha = preds + (size_t)BQ * NSTEP * VV;

    unsigned long long* g_arg = (unsigned long long*)d_ws;   // 240 u64
    float* ws = (float*)d_ws + 480;
    float* att1 = ws; ws += (size_t)BQ * PP * AA;    // 1,097,600
    float* pA   = ws; ws += (size_t)KSA * 8 * NA;    //   175,872
    float* pDE  = ws; ws += (size_t)KSE * 8 * VV;    // 1,440,000 (att1 z1, pD, pE)
    float* mean = ws; ws += BQ * DD;
    float* hbuf = ws; ws += BQ * HH;
    float* cbuf = ws; ws += BQ * HH;
    float* ebuf = ws; ws += BQ * PP;
    float* awe  = ws; ws += BQ * DD;

    // att1 z2/z3 partials live in the preds region of d_out (prologue-only
    // scratch; preds is first really written in step E2, long after att1red).
    float* z2 = preds;
    float* z3 = preds + (size_t)BQ * PP * AA;

    k_mean<<<64, 256, 0, stream>>>(enc, mean, g_arg);
    k_init_hc<<<22, 256, 0, stream>>>(mean, Winh, binh, Winc, binc, hbuf, cbuf);
    k_att1<<<dim3(25, 11, 4), 256, 0, stream>>>(enc, Wea, att1, pDE, z2, z3);
    k_att1red<<<BQ * PP, 256, 0, stream>>>(att1, pDE, z2, z3, bea);
    // A(0) from h0
    k_stepEA<<<NCBA * KSA, 256, 0, stream>>>(hbuf, Wfc, pDE, Wda, Wfb, pA, 1);

    for (int t = 0; t < NSTEP; t++) {
        k_stepBE2<<<NBB + NB2, 256, 0, stream>>>(pA, bda, att1, Wfull, ebuf,
                                                 pDE, bfc, preds, g_arg, t);
        k_stepC<<<256, 256, 0, stream>>>(enc, pA, bfb, ebuf, awe, oalpha, t);
        k_stepD1<<<NCBD * KSD, 256, 0, stream>>>(emb, awe, hbuf, Wih, Whh,
                                                 g_arg, pDE, t);
        k_stepD2<<<88, 256, 0, stream>>>(pDE, bih, bhh, cbuf, hbuf);
        k_stepEA<<<NCBE * KSE + NCBA * KSA, 256, 0, stream>>>(hbuf, Wfc, pDE,
                                                              Wda, Wfb, pA, 0);
    }
    k_stepE2<<<NB2, 256, 0, stream>>>(pDE, bfc, preds, g_arg, NSTEP - 1);
}